// Round 5
// baseline (10386.329 us; speedup 1.0000x reference)
//
#include <hip/hip_runtime.h>
#include <cstdint>
#include <cstddef>

#define DEV __device__ __forceinline__

typedef float  f32x2  __attribute__((ext_vector_type(2)));
typedef float  f32x4  __attribute__((ext_vector_type(4)));
typedef float  f32x16 __attribute__((ext_vector_type(16)));
typedef int    i32x2  __attribute__((ext_vector_type(2)));
typedef int    i32x4  __attribute__((ext_vector_type(4)));
typedef _Float16 f16x2 __attribute__((ext_vector_type(2)));
typedef _Float16 f16x8 __attribute__((ext_vector_type(8)));

constexpr float DT   = 0.5f;
constexpr float DT3  = 0.5f / 3.0f;
constexpr float DT8  = 0.0625f;

constexpr float S5  = 32.0f,   IS5 = 1.0f / 32.0f;
constexpr float S6  = 64.0f,   IS6 = 1.0f / 64.0f;
constexpr float S8  = 256.0f,  IS8 = 1.0f / 256.0f;
constexpr float S11 = 2048.0f;

// ---- LDS map (bytes) ----
// ACT chain (in-place): s_hi[0,16K) s_lo[16K,32K) -> h hi [0,32K) + ALO fp8 [32K,48K) -> f f32 [0,32K)
constexpr int ACT  = 0;
constexpr int SLO  = 16384;
constexpr int ALO  = 32768;
constexpr int ACCS = 49152;    // 32K [64][128]f32 RK4 accumulator (encoder: x_lo / h_enc lo scratch)
constexpr int K1SO = 81920;    // 32K [64][128]f32 k1 / d12
constexpr int B2O  = 114688;   // 1K
constexpr int B3O  = 115712;   // 512
constexpr int U01O = 116224;   // 2K
constexpr int SMEM_BYTES = 118272;

// ---- d_ws map (bytes): weight frag tables (L2-resident) ----
constexpr int WS_W1H = 0;        // f16x8[4096]  (16B)  W1 hi
constexpr int WS_W1L = 65536;    // f16x8[4096]         W1 lo*256 fp16
constexpr int WS_W2H = 131072;   // f16x8[8192]         W2 hi
constexpr int WS_W2L = 262144;   // i32x2[8192]  (8B)   W2 lo*2048 fp8
constexpr int WS_W3H = 327680;   // f16x8[4096]         W3 hi
constexpr int WS_W3L = 393216;   // i32x2[4096]         W3 lo*2048 fp8
// total 425984 B

#define MFMA16(a, b, c) __builtin_amdgcn_mfma_f32_32x32x16_f16((a), (b), (c), 0, 0, 0)

DEV int swz(int off, int m, int mask) { return off ^ ((m & mask) << 4); }

DEV float tanh_fast(float x) {
  float e = __builtin_amdgcn_exp2f(x * 2.885390082f);
  return 1.0f - 2.0f * __builtin_amdgcn_rcpf(e + 1.0f);
}

DEV unsigned pkh2(float a, float b) {
  f16x2 p = { (_Float16)a, (_Float16)b };
  return __builtin_bit_cast(unsigned, p);
}

DEV f16x8 read_f16t(const char* buf, int RS, int m, int kelem, int mask) {
  return *(const f16x8*)(buf + swz(m * RS + kelem * 2, m, mask));
}
DEV i32x2 read8b(const char* buf, int m, int kelem) {   // fp8 plane, RS=256B
  return *(const i32x2*)(buf + swz(m * 256 + kelem, m, 15));
}
DEV f16x8 mulh(f16x8 v, float s) {
  _Float16 h = (_Float16)s;
  f16x8 r;
#pragma unroll
  for (int j = 0; j < 8; ++j) r[j] = v[j] * h;
  return r;
}
DEV f16x8 dec8(i32x2 r, float sc) {
  f32x2 p0 = __builtin_amdgcn_cvt_pk_f32_fp8(r[0], false);
  f32x2 p1 = __builtin_amdgcn_cvt_pk_f32_fp8(r[0], true);
  f32x2 p2 = __builtin_amdgcn_cvt_pk_f32_fp8(r[1], false);
  f32x2 p3 = __builtin_amdgcn_cvt_pk_f32_fp8(r[1], true);
  f16x2 q0 = __builtin_bit_cast(f16x2, __builtin_amdgcn_cvt_pkrtz(p0[0] * sc, p0[1] * sc));
  f16x2 q1 = __builtin_bit_cast(f16x2, __builtin_amdgcn_cvt_pkrtz(p1[0] * sc, p1[1] * sc));
  f16x2 q2 = __builtin_bit_cast(f16x2, __builtin_amdgcn_cvt_pkrtz(p2[0] * sc, p2[1] * sc));
  f16x2 q3 = __builtin_bit_cast(f16x2, __builtin_amdgcn_cvt_pkrtz(p3[0] * sc, p3[1] * sc));
  f16x8 o;
  o[0] = q0[0]; o[1] = q0[1]; o[2] = q1[0]; o[3] = q1[1];
  o[4] = q2[0]; o[5] = q2[1]; o[6] = q3[0]; o[7] = q3[1];
  return o;
}
DEV int pk4fp8(float a, float b, float c, float d) {
  int w = __builtin_amdgcn_cvt_pk_fp8_f32(a, b, 0, false);
  w = __builtin_amdgcn_cvt_pk_fp8_f32(c, d, w, true);
  return w;
}

DEV void cvt_hl_s(const float* p, f16x8& hi, f16x8& lo, float ls) {
  f32x4 a = *(const f32x4*)p;
  f32x4 b = *(const f32x4*)(p + 4);
#pragma unroll
  for (int j = 0; j < 4; ++j) {
    _Float16 h = (_Float16)a[j]; hi[j] = h; lo[j] = (_Float16)((a[j] - (float)h) * ls);
    _Float16 g = (_Float16)b[j]; hi[4 + j] = g; lo[4 + j] = (_Float16)((b[j] - (float)g) * ls);
  }
}

// tanh(acc) -> hi fp16 (RS512, swz31) + lo*2048 fp8 (RS256, swz15)
DEV void write_h8(char* hi, char* lo, f32x16 acc[2][2], int lane, int nbase) {
  const int mr = lane & 31, hh = lane >> 5;
#pragma unroll
  for (int nt = 0; nt < 2; ++nt)
#pragma unroll
    for (int mt = 0; mt < 2; ++mt) {
      int m = mt * 32 + mr;
#pragma unroll
      for (int g = 0; g < 4; ++g) {
        int n = nbase + nt * 32 + 8 * g + 4 * hh;
        float v0 = tanh_fast(acc[nt][mt][4 * g + 0]);
        float v1 = tanh_fast(acc[nt][mt][4 * g + 1]);
        float v2 = tanh_fast(acc[nt][mt][4 * g + 2]);
        float v3 = tanh_fast(acc[nt][mt][4 * g + 3]);
        i32x2 w;
        w[0] = (int)pkh2(v0, v1);
        w[1] = (int)pkh2(v2, v3);
        *(i32x2*)(hi + swz(m * 512 + n * 2, m, 31)) = w;
        float l0 = (v0 - (float)(_Float16)v0) * S11;
        float l1 = (v1 - (float)(_Float16)v1) * S11;
        float l2 = (v2 - (float)(_Float16)v2) * S11;
        float l3 = (v3 - (float)(_Float16)v3) * S11;
        *(int*)(lo + swz(m * 256 + n, m, 15)) = pk4fp8(l0, l1, l2, l3);
      }
    }
}

// encoder: relu(acc) hi fp16 + lo*ls fp16, both RS512 swz31
DEV void write_h16(char* hi, char* lo, f32x16 acc[2][2], int lane, int nbase, float ls) {
  const int mr = lane & 31, hh = lane >> 5;
#pragma unroll
  for (int nt = 0; nt < 2; ++nt)
#pragma unroll
    for (int mt = 0; mt < 2; ++mt) {
      int m = mt * 32 + mr;
#pragma unroll
      for (int g = 0; g < 4; ++g) {
        int n = nbase + nt * 32 + 8 * g + 4 * hh;
        float v0 = fmaxf(acc[nt][mt][4 * g + 0], 0.f);
        float v1 = fmaxf(acc[nt][mt][4 * g + 1], 0.f);
        float v2 = fmaxf(acc[nt][mt][4 * g + 2], 0.f);
        float v3 = fmaxf(acc[nt][mt][4 * g + 3], 0.f);
        i32x2 w;
        w[0] = (int)pkh2(v0, v1); w[1] = (int)pkh2(v2, v3);
        *(i32x2*)(hi + swz(m * 512 + n * 2, m, 31)) = w;
        w[0] = (int)pkh2((v0 - (float)(_Float16)v0) * ls, (v1 - (float)(_Float16)v1) * ls);
        w[1] = (int)pkh2((v2 - (float)(_Float16)v2) * ls, (v3 - (float)(_Float16)v3) * ls);
        *(i32x2*)(lo + swz(m * 512 + n * 2, m, 31)) = w;
      }
    }
}

DEV void write_hc(char* hi, f32x16 acc[2][2], int lane, int nbase) {
  const int mr = lane & 31, hh = lane >> 5;
#pragma unroll
  for (int nt = 0; nt < 2; ++nt)
#pragma unroll
    for (int mt = 0; mt < 2; ++mt) {
      int m = mt * 32 + mr;
#pragma unroll
      for (int g = 0; g < 4; ++g) {
        int n = nbase + nt * 32 + 8 * g + 4 * hh;
        i32x2 w;
        w[0] = (int)pkh2(fmaxf(acc[nt][mt][4 * g + 0], 0.f), fmaxf(acc[nt][mt][4 * g + 1], 0.f));
        w[1] = (int)pkh2(fmaxf(acc[nt][mt][4 * g + 2], 0.f), fmaxf(acc[nt][mt][4 * g + 3], 0.f));
        *(i32x2*)(hi + swz(m * 512 + n * 2, m, 31)) = w;
      }
    }
}

// fp32 D[n][m] -> [64][128]f32 RS512 swz31 @ACT
DEV void write_f32v(char* dst, const f32x16& a0, const f32x16& a1, int lane, int nbase) {
  const int mr = lane & 31, hh = lane >> 5;
#pragma unroll
  for (int mt = 0; mt < 2; ++mt) {
    const f32x16& a = mt ? a1 : a0;
    int m = mt * 32 + mr;
#pragma unroll
    for (int g = 0; g < 4; ++g) {
      int n = nbase + 8 * g + 4 * hh;
      f32x4 v = { a[4 * g + 0], a[4 * g + 1], a[4 * g + 2], a[4 * g + 3] };
      *(f32x4*)(dst + swz(m * 512 + n * 4, m, 31)) = v;
    }
  }
}

DEV void read_kv(const char* sm, int m, int cs, float* kv) {
#pragma unroll
  for (int blk = 0; blk < 8; ++blk) {
    f32x4 v = *(const f32x4*)(sm + ACT + swz(m * 512 + cs * 128 + blk * 16, m, 31));
    kv[4 * blk] = v[0]; kv[4 * blk + 1] = v[1]; kv[4 * blk + 2] = v[2]; kv[4 * blk + 3] = v[3];
  }
}

// owner state (ACCS/K1SO): f32x4 group g (0..7) of row m
DEV f32x4 ld_st(const char* sm, int base, int m, int cs, int g) {
  return *(const f32x4*)(sm + base + swz(m * 512 + cs * 128 + g * 16, m, 31));
}
DEV void st_st(char* sm, int base, int m, int cs, int g, f32x4 v) {
  *(f32x4*)(sm + base + swz(m * 512 + cs * 128 + g * 16, m, 31)) = v;
}

// owners: 8 staged values -> hi fp16 @ACT + lo*32 fp16 @SLO (RS256 swz15)
DEV void write_stage8(char* sm, int m, int cs, int gg, const float* sv) {
  i32x4 wh, wl;
#pragma unroll
  for (int j = 0; j < 4; ++j) {
    float v0 = sv[2 * j], v1 = sv[2 * j + 1];
    _Float16 h0 = (_Float16)v0, h1 = (_Float16)v1;
    f16x2 ph = { h0, h1 };
    f16x2 pl = { (_Float16)((v0 - (float)h0) * S5), (_Float16)((v1 - (float)h1) * S5) };
    wh[j] = __builtin_bit_cast(int, ph);
    wl[j] = __builtin_bit_cast(int, pl);
  }
  int off = swz(m * 256 + cs * 64 + gg * 16, m, 15);
  *(i32x4*)(sm + ACT + off) = wh;
  *(i32x4*)(sm + SLO + off) = wl;
}

// ---- one MLP eval: s (ACT/SLO) -> f (ACT f32). All weights streamed from d_ws tables. ----
DEV void f_eval(char* sm, const char* ws, float t, const f16x8* Au, int lane, int wave) {
  const int mr = lane & 31, kh = (lane >> 5) * 8, hh = lane >> 5;
  const int wb64 = wave * 64, wb32 = wave * 32;
  const f16x8* W1H = (const f16x8*)(ws + WS_W1H) + wave * 1024 + lane;   // + nt*512 + ks*64
  const f16x8* W1L = (const f16x8*)(ws + WS_W1L) + wave * 1024 + lane;
  const f16x8* W2H = (const f16x8*)(ws + WS_W2H) + wave * 2048 + lane;   // + nt*1024 + ks*64
  const i32x2* W2Lo = (const i32x2*)(ws + WS_W2L) + wave * 2048 + lane;
  const f16x8* W3H = (const f16x8*)(ws + WS_W3H) + wave * 1024 + lane;   // + ks*64
  const i32x2* W3Lo = (const i32x2*)(ws + WS_W3L) + wave * 1024 + lane;

  __syncthreads();  // A: stage visible
  f32x16 a1[2][2];
#pragma unroll
  for (int nt = 0; nt < 2; ++nt)
#pragma unroll
    for (int mt = 0; mt < 2; ++mt)
#pragma unroll
      for (int r = 0; r < 16; ++r) a1[nt][mt][r] = 0.f;

  f16x8 wh[2][2], wl[2][2];
  wh[0][0] = W1H[0];  wh[0][1] = W1H[512];      wl[0][0] = W1L[0];  wl[0][1] = W1L[512];
  wh[1][0] = W1H[64]; wh[1][1] = W1H[512 + 64]; wl[1][0] = W1L[64]; wl[1][1] = W1L[512 + 64];
#pragma unroll
  for (int ks = 0; ks < 8; ++ks) {
    f16x8 h0 = wh[ks & 1][0], h1 = wh[ks & 1][1];
    f16x8 l0 = wl[ks & 1][0], l1 = wl[ks & 1][1];
    if (ks + 2 < 8) {
      wh[ks & 1][0] = W1H[(ks + 2) * 64]; wh[ks & 1][1] = W1H[512 + (ks + 2) * 64];
      wl[ks & 1][0] = W1L[(ks + 2) * 64]; wl[ks & 1][1] = W1L[512 + (ks + 2) * 64];
    }
    int ke = ks * 16 + kh;
    f16x8 bh0 = read_f16t(sm + ACT, 256, mr, ke, 15);
    f16x8 bh1 = read_f16t(sm + ACT, 256, 32 + mr, ke, 15);
    f16x8 bl0 = read_f16t(sm + SLO, 256, mr, ke, 15);
    f16x8 bl1 = read_f16t(sm + SLO, 256, 32 + mr, ke, 15);
    f16x8 bh0m = mulh(bh0, IS8), bh1m = mulh(bh1, IS8);
    f16x8 w1s0 = mulh(h0, IS5), w1s1 = mulh(h1, IS5);
    // term1: s_hi @ W1_hi
    a1[0][0] = MFMA16(h0, bh0, a1[0][0]);
    a1[0][1] = MFMA16(h0, bh1, a1[0][1]);
    a1[1][0] = MFMA16(h1, bh0, a1[1][0]);
    a1[1][1] = MFMA16(h1, bh1, a1[1][1]);
    // term2: (s_lo*32) @ (W1_hi/32)
    a1[0][0] = MFMA16(w1s0, bl0, a1[0][0]);
    a1[0][1] = MFMA16(w1s0, bl1, a1[0][1]);
    a1[1][0] = MFMA16(w1s1, bl0, a1[1][0]);
    a1[1][1] = MFMA16(w1s1, bl1, a1[1][1]);
    // term3: (s_hi/256) @ (W1_lo*256)
    a1[0][0] = MFMA16(l0, bh0m, a1[0][0]);
    a1[0][1] = MFMA16(l0, bh1m, a1[0][1]);
    a1[1][0] = MFMA16(l1, bh0m, a1[1][0]);
    a1[1][1] = MFMA16(l1, bh1m, a1[1][1]);
  }
  // U-slice: U0 + t*U1 at ~fp32
  {
    _Float16 th = (_Float16)t;
    _Float16 tl = (_Float16)(t - (float)th);
    f16x8 ub, ul;
#pragma unroll
    for (int j = 0; j < 8; ++j) { ub[j] = (_Float16)0.f; ul[j] = (_Float16)0.f; }
    if (kh == 0) {
      ub[0] = (_Float16)1.0f; ub[1] = th;
      ub[2] = (_Float16)IS8;  ub[3] = (_Float16)((float)th * IS8);
      ul[1] = tl;             ul[3] = (_Float16)((float)tl * IS8);
    }
#pragma unroll
    for (int nt = 0; nt < 2; ++nt) {
      a1[nt][0] = MFMA16(Au[nt], ub, a1[nt][0]);
      a1[nt][1] = MFMA16(Au[nt], ub, a1[nt][1]);
      a1[nt][0] = MFMA16(Au[nt], ul, a1[nt][0]);
      a1[nt][1] = MFMA16(Au[nt], ul, a1[nt][1]);
    }
  }
  __syncthreads();  // G1: s reads done
  write_h8(sm + ACT, sm + ALO, a1, lane, wb64);
  __syncthreads();  // C: h1 ready

  // ---- layer 2 ----
  const float* B2p = (const float*)(sm + B2O);
  f32x16 a2[2][2];
#pragma unroll
  for (int nt = 0; nt < 2; ++nt)
#pragma unroll
    for (int g = 0; g < 4; ++g) {
      int n = wb64 + nt * 32 + 8 * g + 4 * hh;
      f32x4 bv = *(const f32x4*)(B2p + n);
#pragma unroll
      for (int r = 0; r < 4; ++r) { a2[nt][0][4 * g + r] = bv[r]; a2[nt][1][4 * g + r] = bv[r]; }
    }
  f16x8 w2h[2][2]; i32x2 w2l[2][2];
  w2h[0][0] = W2H[0];  w2h[0][1] = W2H[1024];      w2l[0][0] = W2Lo[0];  w2l[0][1] = W2Lo[1024];
  w2h[1][0] = W2H[64]; w2h[1][1] = W2H[1024 + 64]; w2l[1][0] = W2Lo[64]; w2l[1][1] = W2Lo[1024 + 64];
#pragma unroll
  for (int ks = 0; ks < 16; ++ks) {
    f16x8 W2h0 = w2h[ks & 1][0], W2h1 = w2h[ks & 1][1];
    i32x2 t0 = w2l[ks & 1][0], t1 = w2l[ks & 1][1];
    if (ks + 2 < 16) {
      w2h[ks & 1][0] = W2H[(ks + 2) * 64];  w2h[ks & 1][1] = W2H[1024 + (ks + 2) * 64];
      w2l[ks & 1][0] = W2Lo[(ks + 2) * 64]; w2l[ks & 1][1] = W2Lo[1024 + (ks + 2) * 64];
    }
    int ke = ks * 16 + kh;
    f16x8 bh0 = read_f16t(sm + ACT, 512, mr, ke, 31);
    f16x8 bh1 = read_f16t(sm + ACT, 512, 32 + mr, ke, 31);
    f16x8 bl0 = dec8(read8b(sm + ALO, mr, ke), IS6);
    f16x8 bl1 = dec8(read8b(sm + ALO, 32 + mr, ke), IS6);
    f16x8 w2s0 = mulh(W2h0, IS5), w2s1 = mulh(W2h1, IS5);
    f16x8 bh0m = mulh(bh0, IS6), bh1m = mulh(bh1, IS6);
    f16x8 wa0 = dec8(t0, IS5), wa1 = dec8(t1, IS5);
    a2[0][0] = MFMA16(W2h0, bh0, a2[0][0]);
    a2[0][1] = MFMA16(W2h0, bh1, a2[0][1]);
    a2[1][0] = MFMA16(W2h1, bh0, a2[1][0]);
    a2[1][1] = MFMA16(W2h1, bh1, a2[1][1]);
    a2[0][0] = MFMA16(w2s0, bl0, a2[0][0]);
    a2[0][1] = MFMA16(w2s0, bl1, a2[0][1]);
    a2[1][0] = MFMA16(w2s1, bl0, a2[1][0]);
    a2[1][1] = MFMA16(w2s1, bl1, a2[1][1]);
    a2[0][0] = MFMA16(wa0, bh0m, a2[0][0]);
    a2[0][1] = MFMA16(wa0, bh1m, a2[0][1]);
    a2[1][0] = MFMA16(wa1, bh0m, a2[1][0]);
    a2[1][1] = MFMA16(wa1, bh1m, a2[1][1]);
  }
  __syncthreads();  // G2: h1 reads done
  write_h8(sm + ACT, sm + ALO, a2, lane, wb64);
  __syncthreads();  // E: h2 ready

  // ---- layer 3 ----
  const float* B3p = (const float*)(sm + B3O);
  f32x16 a30, a31;
#pragma unroll
  for (int g = 0; g < 4; ++g) {
    int n = wb32 + 8 * g + 4 * hh;
    f32x4 bv = *(const f32x4*)(B3p + n);
#pragma unroll
    for (int r = 0; r < 4; ++r) { a30[4 * g + r] = bv[r]; a31[4 * g + r] = bv[r]; }
  }
  f16x8 w3h[2]; i32x2 w3l[2];
  w3h[0] = W3H[0]; w3h[1] = W3H[64]; w3l[0] = W3Lo[0]; w3l[1] = W3Lo[64];
#pragma unroll
  for (int ks = 0; ks < 16; ++ks) {
    f16x8 W3h = w3h[ks & 1];
    i32x2 t0 = w3l[ks & 1];
    if (ks + 2 < 16) {
      w3h[ks & 1] = W3H[(ks + 2) * 64];
      w3l[ks & 1] = W3Lo[(ks + 2) * 64];
    }
    int ke = ks * 16 + kh;
    f16x8 bh0 = read_f16t(sm + ACT, 512, mr, ke, 31);
    f16x8 bh1 = read_f16t(sm + ACT, 512, 32 + mr, ke, 31);
    f16x8 bl0 = dec8(read8b(sm + ALO, mr, ke), IS6);
    f16x8 bl1 = dec8(read8b(sm + ALO, 32 + mr, ke), IS6);
    f16x8 w3s = mulh(W3h, IS5);
    f16x8 bh0m = mulh(bh0, IS6), bh1m = mulh(bh1, IS6);
    f16x8 wa = dec8(t0, IS5);
    a30 = MFMA16(W3h, bh0, a30);
    a31 = MFMA16(W3h, bh1, a31);
    a30 = MFMA16(w3s, bl0, a30);
    a31 = MFMA16(w3s, bl1, a31);
    a30 = MFMA16(wa, bh0m, a30);
    a31 = MFMA16(wa, bh1m, a31);
  }
  __syncthreads();  // G3: h2 reads done
  write_f32v(sm + ACT, a30, a31, lane, wb32);
  __syncthreads();  // F: f ready
}

// ---- prep: build all weight frag tables in d_ws ----
__global__ void prep_tabs(const float* __restrict__ W1, const float* __restrict__ W2,
                          const float* __restrict__ W3, char* __restrict__ ws) {
  int i = blockIdx.x * 256 + threadIdx.x;   // 0..8191
  int lane = i & 63, mr = lane & 31, kh = (lane >> 5) * 8;
  {
    int ks = (i >> 6) & 15, nt = (i >> 10) & 1, wave = (i >> 11) & 3;
    const float* p = W2 + (size_t)(wave * 64 + nt * 32 + mr) * 256 + ks * 16 + kh;
    f16x8 hi; float l[8];
#pragma unroll
    for (int j = 0; j < 8; ++j) {
      float w = p[j]; _Float16 h = (_Float16)w;
      hi[j] = h; l[j] = (w - (float)h) * S11;
    }
    *(f16x8*)(ws + WS_W2H + (size_t)i * 16) = hi;
    i32x2 wv;
    wv[0] = pk4fp8(l[0], l[1], l[2], l[3]);
    wv[1] = pk4fp8(l[4], l[5], l[6], l[7]);
    *(i32x2*)(ws + WS_W2L + (size_t)i * 8) = wv;
  }
  if (i < 4096) {
    {
      int ks = (i >> 6) & 7, nt = (i >> 9) & 1, wave = (i >> 10) & 3;
      const float* p = W1 + (size_t)(wave * 64 + nt * 32 + mr) * 128 + ks * 16 + kh;
      f16x8 hi, lo;
#pragma unroll
      for (int j = 0; j < 8; ++j) {
        float w = p[j]; _Float16 h = (_Float16)w;
        hi[j] = h; lo[j] = (_Float16)((w - (float)h) * S8);
      }
      *(f16x8*)(ws + WS_W1H + (size_t)i * 16) = hi;
      *(f16x8*)(ws + WS_W1L + (size_t)i * 16) = lo;
    }
    {
      int ks = (i >> 6) & 15, wave = (i >> 10) & 3;
      const float* p = W3 + (size_t)(wave * 32 + mr) * 256 + ks * 16 + kh;
      f16x8 hi; float l[8];
#pragma unroll
      for (int j = 0; j < 8; ++j) {
        float w = p[j]; _Float16 h = (_Float16)w;
        hi[j] = h; l[j] = (w - (float)h) * S11;
      }
      *(f16x8*)(ws + WS_W3H + (size_t)i * 16) = hi;
      i32x2 wv;
      wv[0] = pk4fp8(l[0], l[1], l[2], l[3]);
      wv[1] = pk4fp8(l[4], l[5], l[6], l[7]);
      *(i32x2*)(ws + WS_W3L + (size_t)i * 8) = wv;
    }
  }
}

__global__ __launch_bounds__(256, 1) void node_kernel(
    const float* __restrict__ traj,
    const float* __restrict__ We1, const float* __restrict__ be1,
    const float* __restrict__ We2, const float* __restrict__ be2,
    const float* __restrict__ wte, const float* __restrict__ bte,
    const float* __restrict__ W1,  const float* __restrict__ b1,
    const float* __restrict__ W2,  const float* __restrict__ b2,
    const float* __restrict__ W3,  const float* __restrict__ b3,
    const float* __restrict__ Wc1, const float* __restrict__ bc1,
    const float* __restrict__ Wc2, const float* __restrict__ bc2,
    const char* __restrict__ ws, float* __restrict__ out) {
  __shared__ __align__(16) char sm[SMEM_BYTES];
  const int tid  = threadIdx.x;
  const int lane = tid & 63, wave = tid >> 6;
  const int mr = lane & 31, kh = (lane >> 5) * 8, hh = lane >> 5;
  const int wb64 = wave * 64, wb32 = wave * 32;
  const int brow = blockIdx.x * 64;

  // ---- init: U0/U1 fold, bias tables ----
  {
    int n = tid;
    float u0 = b1[n], u1 = 0.f;
    const float* wr = W1 + n * 128;
    for (int k = 0; k < 128; ++k) { float w = wr[k]; u1 += wte[k] * w; u0 += bte[k] * w; }
    float* U = (float*)(sm + U01O);
    U[2 * n] = u0; U[2 * n + 1] = u1;
    ((float*)(sm + B2O))[n] = b2[n];
    if (n < 128) ((float*)(sm + B3O))[n] = b3[n];
  }
  __syncthreads();  // U01 ready

  // Au: rows n, slots [U0h, U1h, U0l*256, U1l*256]
  f16x8 Au[2];
#pragma unroll
  for (int nt = 0; nt < 2; ++nt) {
    f16x8 a;
#pragma unroll
    for (int j = 0; j < 8; ++j) a[j] = (_Float16)0.f;
    if (kh == 0) {
      const float* U = (const float*)(sm + U01O);
      int n = wb64 + nt * 32 + mr;
      float u0 = U[2 * n], u1 = U[2 * n + 1];
      _Float16 u0h = (_Float16)u0, u1h = (_Float16)u1;
      a[0] = u0h; a[1] = u1h;
      a[2] = (_Float16)((u0 - (float)u0h) * S8);
      a[3] = (_Float16)((u1 - (float)u1h) * S8);
    }
    Au[nt] = a;
  }

  const int m_own = tid >> 2, cs = tid & 3;

  // ---- encoder: x hi@ACT (RS512), x lo*64 @ACCS scratch (RS512) ----
  f32x16 ae[2][2];
#pragma unroll
  for (int nt = 0; nt < 2; ++nt)
#pragma unroll
    for (int mt = 0; mt < 2; ++mt)
#pragma unroll
      for (int r = 0; r < 16; ++r) ae[nt][mt][r] = 0.f;

  for (int c = 0; c < 3; ++c) {
#pragma unroll
    for (int g = 0; g < 8; ++g) {
      const float* xp = traj + (size_t)(brow + m_own) * 7168 + c * 256 + cs * 64 + g * 8;
      f32x4 a = *(const f32x4*)xp;
      f32x4 b = *(const f32x4*)(xp + 4);
      i32x4 wh, wl;
#pragma unroll
      for (int j = 0; j < 2; ++j) {
        float v0 = a[2 * j], v1 = a[2 * j + 1];
        _Float16 h0 = (_Float16)v0, h1 = (_Float16)v1;
        f16x2 ph = { h0, h1 };
        f16x2 pl = { (_Float16)((v0 - (float)h0) * S6), (_Float16)((v1 - (float)h1) * S6) };
        wh[j] = __builtin_bit_cast(int, ph); wl[j] = __builtin_bit_cast(int, pl);
        float w0 = b[2 * j], w1 = b[2 * j + 1];
        _Float16 g0 = (_Float16)w0, g1 = (_Float16)w1;
        f16x2 qh = { g0, g1 };
        f16x2 ql = { (_Float16)((w0 - (float)g0) * S6), (_Float16)((w1 - (float)g1) * S6) };
        wh[2 + j] = __builtin_bit_cast(int, qh); wl[2 + j] = __builtin_bit_cast(int, ql);
      }
      int off = swz(m_own * 512 + cs * 128 + g * 16, m_own, 31);
      *(i32x4*)(sm + ACT + off) = wh;
      *(i32x4*)(sm + ACCS + off) = wl;
    }
    __syncthreads();
#pragma unroll
    for (int ks = 0; ks < 16; ++ks) {
      int ke = ks * 16 + kh;
      f16x8 bh0 = read_f16t(sm + ACT, 512, mr, ke, 31);
      f16x8 bh1 = read_f16t(sm + ACT, 512, 32 + mr, ke, 31);
      f16x8 bl0 = read_f16t(sm + ACCS, 512, mr, ke, 31);
      f16x8 bl1 = read_f16t(sm + ACCS, 512, 32 + mr, ke, 31);
      f16x8 bh0m = mulh(bh0, IS6), bh1m = mulh(bh1, IS6);
#pragma unroll
      for (int nt = 0; nt < 2; ++nt) {
        f16x8 wh, wl;
        cvt_hl_s(We1 + (size_t)(wb64 + nt * 32 + mr) * 768 + c * 256 + ks * 16 + kh, wh, wl, S6);
        f16x8 whs = mulh(wh, IS6);
        ae[nt][0] = MFMA16(wh, bh0, ae[nt][0]);
        ae[nt][1] = MFMA16(wh, bh1, ae[nt][1]);
        ae[nt][0] = MFMA16(whs, bl0, ae[nt][0]);
        ae[nt][1] = MFMA16(whs, bl1, ae[nt][1]);
        ae[nt][0] = MFMA16(wl, bh0m, ae[nt][0]);
        ae[nt][1] = MFMA16(wl, bh1m, ae[nt][1]);
      }
    }
    __syncthreads();
  }
#pragma unroll
  for (int nt = 0; nt < 2; ++nt)
#pragma unroll
    for (int r = 0; r < 16; ++r) {
      int n = wb64 + nt * 32 + (r & 3) + 8 * (r >> 2) + 4 * hh;
      float bv = be1[n];
      ae[nt][0][r] += bv; ae[nt][1][r] += bv;
    }
  write_h16(sm + ACT, sm + ACCS, ae, lane, wb64, S6);   // h_enc hi@ACT, lo*64@ACCS
  __syncthreads();

  {
    f32x16 az0, az1;
#pragma unroll
    for (int r = 0; r < 16; ++r) { az0[r] = 0.f; az1[r] = 0.f; }
#pragma unroll
    for (int ks = 0; ks < 16; ++ks) {
      int ke = ks * 16 + kh;
      f16x8 bh0 = read_f16t(sm + ACT, 512, mr, ke, 31);
      f16x8 bh1 = read_f16t(sm + ACT, 512, 32 + mr, ke, 31);
      f16x8 bl0 = read_f16t(sm + ACCS, 512, mr, ke, 31);
      f16x8 bl1 = read_f16t(sm + ACCS, 512, 32 + mr, ke, 31);
      f16x8 bh0m = mulh(bh0, IS6), bh1m = mulh(bh1, IS6);
      f16x8 wh, wl;
      cvt_hl_s(We2 + (size_t)(wb32 + mr) * 256 + ks * 16 + kh, wh, wl, S6);
      f16x8 whs = mulh(wh, IS6);
      az0 = MFMA16(wh, bh0, az0);
      az1 = MFMA16(wh, bh1, az1);
      az0 = MFMA16(whs, bl0, az0);
      az1 = MFMA16(whs, bl1, az1);
      az0 = MFMA16(wl, bh0m, az0);
      az1 = MFMA16(wl, bh1m, az1);
    }
#pragma unroll
    for (int r = 0; r < 16; ++r) {
      int n = wb32 + (r & 3) + 8 * (r >> 2) + 4 * hh;
      float bv = be2[n];
      az0[r] += bv; az1[r] += bv;
    }
    __syncthreads();                    // h_enc reads done
    write_f32v(sm + ACT, az0, az1, lane, wb32);  // z0 in f layout
    __syncthreads();
  }

  // ---- owners pick up z0; write frame 0 ----
  float z[32];
  read_kv(sm, m_own, cs, z);
  float* outz = out + 16384;
  {
    float* p = outz + (size_t)(brow + m_own) * 128 + cs * 32;
#pragma unroll
    for (int g = 0; g < 8; ++g) {
      f32x4 v = { z[4 * g], z[4 * g + 1], z[4 * g + 2], z[4 * g + 3] };
      *(f32x4*)(p + 4 * g) = v;
    }
  }

  // ---- RK4 (3/8 rule), 54 steps; Acc/k1 state in LDS ----
  for (int st = 0; st < 54; ++st) {
    float t0 = st * 0.5f;
    __syncthreads();  // H: f/z0 reads done
#pragma unroll
    for (int gg = 0; gg < 4; ++gg) write_stage8(sm, m_own, cs, gg, z + 8 * gg);  // s1 = z
    f_eval(sm, ws, t0, Au, lane, wave);                         // k1
    {
      float kv[32];
      read_kv(sm, m_own, cs, kv);
      __syncthreads();
#pragma unroll
      for (int gg = 0; gg < 4; ++gg) {
        float sv[8];
#pragma unroll
        for (int h = 0; h < 2; ++h) {
          int g = 2 * gg + h;
          f32x4 k = { kv[4 * g], kv[4 * g + 1], kv[4 * g + 2], kv[4 * g + 3] };
          f32x4 a, s;
#pragma unroll
          for (int j = 0; j < 4; ++j) {
            int e = 4 * g + j;
            a[j] = z[e] + DT8 * k[j];
            s[j] = z[e] + DT3 * k[j];
          }
          st_st(sm, ACCS, m_own, cs, g, a);
          st_st(sm, K1SO, m_own, cs, g, k);
          sv[4 * h] = s[0]; sv[4 * h + 1] = s[1]; sv[4 * h + 2] = s[2]; sv[4 * h + 3] = s[3];
        }
        write_stage8(sm, m_own, cs, gg, sv);
      }
    }
    f_eval(sm, ws, t0 + DT3, Au, lane, wave);                   // k2
    {
      float kv[32];
      read_kv(sm, m_own, cs, kv);
      __syncthreads();
#pragma unroll
      for (int gg = 0; gg < 4; ++gg) {
        float sv[8];
#pragma unroll
        for (int h = 0; h < 2; ++h) {
          int g = 2 * gg + h;
          f32x4 k1 = ld_st(sm, K1SO, m_own, cs, g);
          f32x4 a  = ld_st(sm, ACCS, m_own, cs, g);
          f32x4 d12, an;
#pragma unroll
          for (int j = 0; j < 4; ++j) {
            int e = 4 * g + j;
            float k2 = kv[e];
            an[j] = a[j] + 3.0f * DT8 * k2;
            sv[4 * h + j] = z[e] + DT * k2 - DT3 * k1[j];
            d12[j] = k1[j] - k2;
          }
          st_st(sm, ACCS, m_own, cs, g, an);
          st_st(sm, K1SO, m_own, cs, g, d12);
        }
        write_stage8(sm, m_own, cs, gg, sv);
      }
    }
    f_eval(sm, ws, t0 + 2.0f * DT3, Au, lane, wave);            // k3
    {
      float kv[32];
      read_kv(sm, m_own, cs, kv);
      __syncthreads();
#pragma unroll
      for (int gg = 0; gg < 4; ++gg) {
        float sv[8];
#pragma unroll
        for (int h = 0; h < 2; ++h) {
          int g = 2 * gg + h;
          f32x4 d12 = ld_st(sm, K1SO, m_own, cs, g);
          f32x4 a   = ld_st(sm, ACCS, m_own, cs, g);
          f32x4 an;
#pragma unroll
          for (int j = 0; j < 4; ++j) {
            int e = 4 * g + j;
            float k3 = kv[e];
            an[j] = a[j] + 3.0f * DT8 * k3;
            sv[4 * h + j] = z[e] + DT * (d12[j] + k3);
          }
          st_st(sm, ACCS, m_own, cs, g, an);
        }
        write_stage8(sm, m_own, cs, gg, sv);
      }
    }
    f_eval(sm, ws, t0 + DT, Au, lane, wave);                    // k4
    {
      float kv[32];
      read_kv(sm, m_own, cs, kv);
#pragma unroll
      for (int g = 0; g < 8; ++g) {
        f32x4 a = ld_st(sm, ACCS, m_own, cs, g);
#pragma unroll
        for (int j = 0; j < 4; ++j) z[4 * g + j] = a[j] + DT8 * kv[4 * g + j];
      }
    }
    if (st & 1) {
      int frame = (st >> 1) + 1;
      float* p = outz + (size_t)frame * 2097152 + (size_t)(brow + m_own) * 128 + cs * 32;
#pragma unroll
      for (int g = 0; g < 8; ++g) {
        f32x4 v = { z[4 * g], z[4 * g + 1], z[4 * g + 2], z[4 * g + 3] };
        *(f32x4*)(p + 4 * g) = v;
      }
    }
  }

  // ---- classifier ----
  __syncthreads();  // f reads done
#pragma unroll
  for (int gg = 0; gg < 4; ++gg) write_stage8(sm, m_own, cs, gg, z + 8 * gg);
  __syncthreads();
  f32x16 ac[2][2];
#pragma unroll
  for (int nt = 0; nt < 2; ++nt)
#pragma unroll
    for (int r = 0; r < 16; ++r) {
      int n = wb64 + nt * 32 + (r & 3) + 8 * (r >> 2) + 4 * hh;
      float bv = bc1[n];
      ac[nt][0][r] = bv; ac[nt][1][r] = bv;
    }
#pragma unroll
  for (int ks = 0; ks < 8; ++ks) {
    int ke = ks * 16 + kh;
    f16x8 bh0 = read_f16t(sm + ACT, 256, mr, ke, 15);
    f16x8 bh1 = read_f16t(sm + ACT, 256, 32 + mr, ke, 15);
    f16x8 bl0 = read_f16t(sm + SLO, 256, mr, ke, 15);
    f16x8 bl1 = read_f16t(sm + SLO, 256, 32 + mr, ke, 15);
#pragma unroll
    for (int nt = 0; nt < 2; ++nt) {
      f16x8 wh, wl;
      cvt_hl_s(Wc1 + (size_t)(wb64 + nt * 32 + mr) * 128 + ks * 16 + kh, wh, wl, 1.0f);
      f16x8 whs = mulh(wh, IS5);
      ac[nt][0] = MFMA16(wh, bh0, ac[nt][0]);
      ac[nt][1] = MFMA16(wh, bh1, ac[nt][1]);
      ac[nt][0] = MFMA16(whs, bl0, ac[nt][0]);
      ac[nt][1] = MFMA16(whs, bl1, ac[nt][1]);
      ac[nt][0] = MFMA16(wl, bh0, ac[nt][0]);
      ac[nt][1] = MFMA16(wl, bh1, ac[nt][1]);
    }
  }
  __syncthreads();  // s reads done
  write_hc(sm + ACT, ac, lane, wb64);
  __syncthreads();
  if (tid < 64) {
    float acc = bc2[0];
#pragma unroll 8
    for (int c0 = 0; c0 < 256; c0 += 8) {
      f16x8 hv = read_f16t(sm + ACT, 512, tid, c0, 31);
#pragma unroll
      for (int j = 0; j < 8; ++j) acc += (float)hv[j] * Wc2[c0 + j];
    }
    out[brow + tid] = __builtin_amdgcn_rcpf(1.0f + __builtin_amdgcn_exp2f(-acc * 1.442695041f));
  }
}

extern "C" void kernel_launch(void* const* d_in, const int* in_sizes, int n_in,
                              void* d_out, int out_size, void* d_ws, size_t ws_size,
                              hipStream_t stream) {
  (void)in_sizes; (void)n_in; (void)out_size; (void)ws_size;
  const float* traj = (const float*)d_in[0];
  const float* We1  = (const float*)d_in[1];
  const float* be1  = (const float*)d_in[2];
  const float* We2  = (const float*)d_in[3];
  const float* be2  = (const float*)d_in[4];
  const float* wte  = (const float*)d_in[5];
  const float* bte  = (const float*)d_in[6];
  const float* W1   = (const float*)d_in[7];
  const float* b1   = (const float*)d_in[8];
  const float* W2   = (const float*)d_in[9];
  const float* b2   = (const float*)d_in[10];
  const float* W3   = (const float*)d_in[11];
  const float* b3   = (const float*)d_in[12];
  const float* Wc1  = (const float*)d_in[13];
  const float* bc1  = (const float*)d_in[14];
  const float* Wc2  = (const float*)d_in[15];
  const float* bc2  = (const float*)d_in[16];
  char* ws = (char*)d_ws;
  hipLaunchKernelGGL(prep_tabs, dim3(32), dim3(256), 0, stream, W1, W2, W3, ws);
  hipLaunchKernelGGL(node_kernel, dim3(256), dim3(256), 0, stream,
                     traj, We1, be1, We2, be2, wte, bte, W1, b1, W2, b2, W3, b3,
                     Wc1, bc1, Wc2, bc2, (const char*)ws, (float*)d_out);
}